// Round 10
// baseline (841.716 us; speedup 1.0000x reference)
//
#include <hip/hip_runtime.h>
#include <hip/hip_bf16.h>
#include <stdint.h>

typedef float f32x4 __attribute__((ext_vector_type(4)));
typedef short bf16x8 __attribute__((ext_vector_type(8)));

__device__ __forceinline__ ushort to_bf16(float f) {
    union { float f; uint32_t u; } v; v.f = f;
    uint32_t u = v.u;
    return (ushort)((u + 0x7fffu + ((u >> 16) & 1u)) >> 16);   // RNE
}
__device__ __forceinline__ float sigmoid_(float x) { return 1.0f / (1.0f + __expf(-x)); }
__device__ __forceinline__ float tanh_(float x)    { return 1.0f - 2.0f / (__expf(2.0f * x) + 1.0f); }

// Swizzled concat weight W'[g][k] = (k<384 ? w_ih : w_hh), bf16; fragment layout:
// elem ((tile*24 + kc)*64 + quad*16 + (g&15))*8 + j  for k = kc*32 + quad*8 + j
__global__ void prep_w(const float* __restrict__ w_ih, const float* __restrict__ w_hh,
                       ushort* __restrict__ wswz) {
    int tid = blockIdx.x * blockDim.x + threadIdx.x;   // 1152 * 96
    if (tid >= 1152 * 96) return;
    int g  = tid / 96;
    int k  = (tid % 96) * 8;
    int kc = k >> 5;
    int q  = (k >> 3) & 3;
    int tile = g >> 4;
    int lane = q * 16 + (g & 15);
    ushort* dst = wswz + ((size_t)(tile * 24 + kc) * 64 + lane) * 8;
    const float* src = (k < 384) ? (w_ih + (size_t)g * 384 + k)
                                 : (w_hh + (size_t)g * 384 + (k - 384));
#pragma unroll
    for (int j = 0; j < 8; ++j) dst[j] = to_bf16(src[j]);
}

__global__ void embed_gather(const int* __restrict__ tok, const float* __restrict__ table,
                             ushort* __restrict__ xleaf, int n_leaves) {
    int tid = blockIdx.x * blockDim.x + threadIdx.x;   // n_leaves * 48
    if (tid >= n_leaves * 48) return;
    int leaf = tid / 48, i = tid % 48;
    const float* src = table + (size_t)tok[leaf] * 384 + i * 8;
    bf16x8 v;
#pragma unroll
    for (int j = 0; j < 8; ++j) v[j] = (short)to_bf16(src[j]);
    *(bf16x8*)(xleaf + (size_t)leaf * 384 + i * 8) = v;
}

#define MFMA(a, b, c) __builtin_amdgcn_mfma_f32_16x16x32_bf16((a), (b), (c), 0, 0, 0)

__device__ __forceinline__ bf16x8 cvt8(f32x4 a, f32x4 b) {
    bf16x8 o;
    o[0] = (short)to_bf16(a[0]); o[1] = (short)to_bf16(a[1]);
    o[2] = (short)to_bf16(a[2]); o[3] = (short)to_bf16(a[3]);
    o[4] = (short)to_bf16(b[0]); o[5] = (short)to_bf16(b[1]);
    o[6] = (short)to_bf16(b[2]); o[7] = (short)to_bf16(b[3]);
    return o;
}

// One GRU step, one launch (launch boundary = the barrier; in-kernel cross-block
// barriers fence-storm — measured r6/r7). No LDS. Block = 256 thr (4 waves);
// wave owns 32 rows (2 m-tiles); block owns 16 dims (ds = blockIdx.y in [0,24)),
// gate triple (r,z,n) -> GRU update lane-local.
// h state: f32 HT only; A-fragments built on the fly (f32 -> RNE bf16, identical
// numerics to a stored-bf16 mirror). ALL h/Xo STORES ARE NON-TEMPORAL: they are
// read only next step / next level, and letting them allocate L2 lines is what
// evicted W each step (r9: FETCH 30 MB/step = W refetch). In-step resident set
// = W 1.77 + x .39 + HT_in .79 = 2.95 MB < 4 MiB -> W stays L2-resident.
// Grid (gx, 24), gx % 8 == 0 (for P>=128) colocates a group's 24 ds-blocks on
// one XCD. flags: 1 = h_prev zero (leaf t0), 2 = last step.
__global__ __launch_bounds__(256, 4)
void gru_step(const ushort* __restrict__ Xc, float* __restrict__ HT,
              const ushort* __restrict__ W, const float* __restrict__ b_ih,
              const float* __restrict__ b_hh, ushort* __restrict__ Xo,
              float* __restrict__ HTn, float* __restrict__ fout,
              int P, int Pn, int t, int flags) {
    const int wave = threadIdx.x >> 6, lane = threadIdx.x & 63;
    const int quad = lane >> 4, col = lane & 15;
    const int m0 = (blockIdx.x * 4 + wave) * 32;
    if (m0 >= P) return;
    const int ds = blockIdx.y;
    const bool hz = (flags & 1) != 0, last = (flags & 2) != 0;
    const bool do2 = (m0 + 16) < P;                  // wave-uniform
    const int child = 7 - t;
    const size_t N = (size_t)P * 384;

    const float* HTp = HT + (size_t)t * N;
    float*       HTc = HT + (size_t)(t + 1) * N;

    const int par0 = m0 + col, par1 = m0 + 16 + col;
    const bool av0 = par0 < P, av1 = par1 < P;
    const ushort* xr0 = Xc + ((size_t)par0 * 8 + child) * 384 + quad * 8;
    const ushort* xr1 = Xc + ((size_t)par1 * 8 + child) * 384 + quad * 8;
    const float*  hr0 = HTp + (size_t)par0 * 384 + quad * 8;
    const float*  hr1 = HTp + (size_t)par1 * 384 + quad * 8;
    const ushort* Wl = W + (size_t)lane * 8;
    const size_t oR = (size_t)ds * 12288;
    const size_t oZ = (size_t)(24 + ds) * 12288;
    const size_t oN = (size_t)(48 + ds) * 12288;

    const int d = ds * 16 + col;
    const float br = b_ih[d] + b_hh[d];
    const float bz = b_ih[384 + d] + b_hh[384 + d];
    const float bi = b_ih[768 + d], bh = b_hh[768 + d];
    float hp[2][4];
#pragma unroll
    for (int mt = 0; mt < 2; ++mt)
#pragma unroll
        for (int r = 0; r < 4; ++r) {
            const int m = m0 + mt * 16 + quad * 4 + r;
            hp[mt][r] = (!hz && m < P) ? HTp[(size_t)m * 384 + d] : 0.0f;
        }

    const f32x4 z4 = (f32x4){0.f, 0.f, 0.f, 0.f};
    const bf16x8 zf = (bf16x8){0, 0, 0, 0, 0, 0, 0, 0};
    f32x4 ar0 = z4, az0 = z4, an10 = z4, an20 = z4;
    f32x4 ar1 = z4, az1 = z4, an11 = z4, an21 = z4;

    // x half (W_ih columns, kc 0..11), A = bf16 x
#pragma unroll
    for (int kc = 0; kc < 12; ++kc) {
        bf16x8 a0 = av0 ? *(const bf16x8*)(xr0 + kc * 32) : zf;
        bf16x8 a1 = (do2 && av1) ? *(const bf16x8*)(xr1 + kc * 32) : zf;
        const size_t kb = (size_t)kc * 512;
        const bf16x8 bR = *(const bf16x8*)(Wl + oR + kb);
        const bf16x8 bZ = *(const bf16x8*)(Wl + oZ + kb);
        const bf16x8 bN = *(const bf16x8*)(Wl + oN + kb);
        ar0  = MFMA(a0, bR, ar0);
        az0  = MFMA(a0, bZ, az0);
        an10 = MFMA(a0, bN, an10);
        if (do2) {
            ar1  = MFMA(a1, bR, ar1);
            az1  = MFMA(a1, bZ, az1);
            an11 = MFMA(a1, bN, an11);
        }
    }
    // h half (W_hh columns, kc 12..23), A = f32 h -> on-the-fly bf16 (RNE)
    if (!hz) {
#pragma unroll
        for (int kc = 0; kc < 12; ++kc) {
            bf16x8 a0 = zf, a1 = zf;
            if (av0) {
                const f32x4* s = (const f32x4*)(hr0 + kc * 32);
                a0 = cvt8(s[0], s[1]);
            }
            if (do2 && av1) {
                const f32x4* s = (const f32x4*)(hr1 + kc * 32);
                a1 = cvt8(s[0], s[1]);
            }
            const size_t kb = (size_t)(12 + kc) * 512;
            const bf16x8 bR = *(const bf16x8*)(Wl + oR + kb);
            const bf16x8 bZ = *(const bf16x8*)(Wl + oZ + kb);
            const bf16x8 bN = *(const bf16x8*)(Wl + oN + kb);
            ar0  = MFMA(a0, bR, ar0);
            az0  = MFMA(a0, bZ, az0);
            an20 = MFMA(a0, bN, an20);
            if (do2) {
                ar1  = MFMA(a1, bR, ar1);
                az1  = MFMA(a1, bZ, az1);
                an21 = MFMA(a1, bN, an21);
            }
        }
    }

    // epilogue: lane-local GRU update; at t==7 node-mean + parent h0
#pragma unroll
    for (int mt = 0; mt < 2; ++mt) {
        if (mt && !do2) break;
        const f32x4 ar  = mt ? ar1  : ar0;
        const f32x4 az  = mt ? az1  : az0;
        const f32x4 an1 = mt ? an11 : an10;
        const f32x4 an2 = mt ? an21 : an20;
        float s4 = 0.0f;
#pragma unroll
        for (int r = 0; r < 4; ++r) {
            const int m = m0 + mt * 16 + quad * 4 + r;
            if (m < P) {
                const size_t idx = (size_t)m * 384 + d;
                const float rv = sigmoid_(ar[r] + br);
                const float zv = sigmoid_(az[r] + bz);
                const float nv = tanh_(an1[r] + bi + rv * (an2[r] + bh));
                const float hn = (1.0f - zv) * nv + zv * hp[mt][r];
                s4 += hn;
                if (!last) {
                    __builtin_nontemporal_store(hn, &HTc[idx]);   // read next step only
                } else {
                    // node out = mean(h1..h8) = (slots 1..6 + hp(=h7) + hn)/8
                    float xs = hn + hp[mt][r];
#pragma unroll
                    for (int s = 1; s <= 6; ++s)
                        xs += __builtin_nontemporal_load(&HT[(size_t)s * N + idx]);
                    const float xo = xs * 0.125f;
                    __builtin_nontemporal_store((ushort)to_bf16(xo), &Xo[idx]);
                    if (fout != nullptr && m == 0) fout[d] = xo;
                }
            }
        }
        // parent h0 = mean of this node's 8 children h8 (quad pairs (0,1),(2,3))
        if (last && HTn != nullptr) {
            const float o = __shfl_xor(s4, 16, 64);
            if ((quad & 1) == 0) {
                const int ti = (m0 >> 4) + mt;
                const int pnode = 2 * ti + (quad >> 1);
                if (pnode < Pn) {
                    const float h0 = (s4 + o) * 0.125f;
                    __builtin_nontemporal_store(h0, &HTn[(size_t)pnode * 384 + d]);
                }
            }
        }
    }
}

extern "C" void kernel_launch(void* const* d_in, const int* in_sizes, int n_in,
                              void* d_out, int out_size, void* d_ws, size_t ws_size,
                              hipStream_t stream) {
    const int*   tok   = (const int*)d_in[0];
    const float* table = (const float*)d_in[1];
    const float* w_ih  = (const float*)d_in[2];
    const float* w_hh  = (const float*)d_in[3];
    const float* b_ih  = (const float*)d_in[4];
    const float* b_hh  = (const float*)d_in[5];
    float* out = (float*)d_out;

    char* ws = (char*)d_ws;
    size_t off = 0;
    auto alloc = [&](size_t bytes) -> void* {
        void* p = ws + off;
        off = (off + bytes + 255) & ~(size_t)255;
        return p;
    };
    ushort* wswz = (ushort*)alloc((size_t)1152 * 768 * 2);
    ushort* XA   = (ushort*)alloc((size_t)32768 * 384 * 2);

    struct Lvl { ushort* Xo; float* HT; int P; };
    auto mk = [&](int P) -> Lvl {
        Lvl l; l.P = P;
        size_t N = (size_t)P * 384;
        l.HT = (float*) alloc(8 * N * 4);   // f32 h slots 0..7
        l.Xo = (ushort*)alloc(N * 2);
        return l;
    };
    Lvl L[5] = {mk(4096), mk(512), mk(64), mk(8), mk(1)};

    prep_w<<<(1152 * 96 + 255) / 256, 256, 0, stream>>>(w_ih, w_hh, wswz);
    embed_gather<<<(32768 * 48 + 255) / 256, 256, 0, stream>>>(tok, table, XA, 32768);

    for (int lv = 0; lv < 5; ++lv) {
        const ushort* Xc = (lv == 0) ? XA : L[lv - 1].Xo;
        int P = L[lv].P;
        int Pn = (lv < 4) ? L[lv + 1].P : 0;
        float* HTn = (lv < 4) ? L[lv + 1].HT : nullptr;
        int gx = (P + 127) / 128;
        if (P >= 128) gx = (gx + 7) & ~7;   // XCD colocation of a group's ds-blocks
        dim3 grid(gx, 24);
        for (int t = 0; t < 8; ++t) {
            int flags = ((lv == 0 && t == 0) ? 1 : 0) | (t == 7 ? 2 : 0);
            gru_step<<<grid, 256, 0, stream>>>(
                Xc, L[lv].HT, wswz, b_ih, b_hh, L[lv].Xo,
                (t == 7) ? HTn : nullptr, (lv == 4 && t == 7) ? out : nullptr,
                P, Pn, t, flags);
        }
    }
}